// Round 13
// baseline (97.539 us; speedup 1.0000x reference)
//
#include <hip/hip_runtime.h>
#include <stdint.h>

#define N_TOK 16384
#define F_DIM 128
#define U_DIM 64
#define E_DIM 32

typedef __bf16 bf16x8 __attribute__((ext_vector_type(8)));
typedef float  floatx4 __attribute__((ext_vector_type(4)));

#define MFMA16(a, b, c) __builtin_amdgcn_mfma_f32_16x16x32_bf16((a), (b), (c), 0, 0, 0)

__device__ __forceinline__ unsigned short f2bf(float f) {
  union { float f; unsigned u; } v; v.f = f;
  unsigned r = v.u + 0x7FFFu + ((v.u >> 16) & 1u);  // RNE
  return (unsigned short)(r >> 16);
}

// ---------------------------------------------------------------------------
// Single-kernel version: prep ELIMINATED. R12 proved the expert loop is
// insensitive to B byte volume, so we read We as fp32 directly (2x bytes)
// and convert to bf16 fragments at CONSUME time (keeps the depth-3 latency
// horizon: eager conversion would force the s_waitcnt at issue site).
// Deletes: prep dispatch, inter-kernel gap, ws write->read round-trip.
// Ring: float bw[4][4][8], &3 indexing + unroll 4 (the only SROA-proven
// recipe, R5-R7 post-mortems). VGPR ~210 -> launch_bounds(512,1) (cap 256).
// Load pattern per (ks,j): lanes 0-15 read 64B contiguous (u fastest in We),
// 4 quads = 4 segments/instr — acceptable coalescing, one-time-streamed.
// f2bf order identical to the old prep -> bit-identical output.
// Everything else (x staging, gate, A fragments, epilogue, store) is the
// proven R1 structure unchanged.
// ---------------------------------------------------------------------------
__global__ __launch_bounds__(512, 1) void moe_main(
    const float* __restrict__ x,
    const float* __restrict__ Wg,
    const float* __restrict__ bg,
    const float* __restrict__ We,
    const float* __restrict__ be,
    float* __restrict__ out) {
  __shared__ unsigned short Xs[64 * 136];  // padded rows
  __shared__ float Gs[E_DIM][68];          // gate [e][row], padded

  const int tid  = threadIdx.x;
  const int lane = tid & 63;
  const int wid  = tid >> 6;       // 0..7
  const int quad = lane >> 4;
  const int l15  = lane & 15;
  const int wr   = wid >> 2;       // 0..1 row half
  const int wc   = wid & 3;        // 0..3 u quarter
  const int u    = wc * 16 + l15;
  const int base = blockIdx.x * 64;

  // ---- B ring: raw fp32, depth 4, prefetch experts 0..2 before anything.
  // bw[c][ks][j] = We[e][ks*32+quad*8+j][u]
  float bw[4][4][8];
  float bevb[4];
  {
    const float* wsrc = We + (size_t)(quad * 8) * 64 + u;
#pragma unroll
    for (int e0 = 0; e0 < 3; e0++) {
#pragma unroll
      for (int ks = 0; ks < 4; ks++)
#pragma unroll
        for (int j = 0; j < 8; j++)
          bw[e0][ks][j] = wsrc[(size_t)e0 * 8192 + (ks * 32 + j) * 64];
      bevb[e0] = be[e0 * U_DIM + u];
    }
  }

  // ---- stage X tile (fp32 -> bf16) into LDS: 512 thr x 16 floats = 64x128
  {
    const int row = tid >> 3;
    const int c16 = tid & 7;
    const float4* src = (const float4*)(x + (size_t)(base + row) * F_DIM + c16 * 16);
    float4 v0 = src[0], v1 = src[1], v2 = src[2], v3 = src[3];
    union { unsigned short us[16]; uint4 q[2]; } pk;
    pk.us[0]  = f2bf(v0.x); pk.us[1]  = f2bf(v0.y); pk.us[2]  = f2bf(v0.z); pk.us[3]  = f2bf(v0.w);
    pk.us[4]  = f2bf(v1.x); pk.us[5]  = f2bf(v1.y); pk.us[6]  = f2bf(v1.z); pk.us[7]  = f2bf(v1.w);
    pk.us[8]  = f2bf(v2.x); pk.us[9]  = f2bf(v2.y); pk.us[10] = f2bf(v2.z); pk.us[11] = f2bf(v2.w);
    pk.us[12] = f2bf(v3.x); pk.us[13] = f2bf(v3.y); pk.us[14] = f2bf(v3.z); pk.us[15] = f2bf(v3.w);
    uint4* dst = (uint4*)&Xs[row * 136 + c16 * 16];
    dst[0] = pk.q[0];
    dst[1] = pk.q[1];
  }
  __syncthreads();  // barrier 1: X ready

  // ---- gate: 8 waves, wave = (rowgroup rg, expert-half et). Wg read fp32
  // directly (one-time): wb[j] = Wg[(ks*32+quad*8+j)][et*16+l15]
  {
    const int rg = wid >> 1;   // 0..3 -> rows rg*16..
    const int et = wid & 1;    // 0..1 -> experts et*16..
    bf16x8 ag[4];
#pragma unroll
    for (int ks = 0; ks < 4; ks++)
      ag[ks] = *(const bf16x8*)&Xs[(rg * 16 + l15) * 136 + ks * 32 + quad * 8];
    floatx4 g = {0.f, 0.f, 0.f, 0.f};
#pragma unroll
    for (int ks = 0; ks < 4; ks++) {
      union { unsigned short us[8]; bf16x8 v; } p;
#pragma unroll
      for (int j = 0; j < 8; j++)
        p.us[j] = f2bf(Wg[(size_t)(ks * 32 + quad * 8 + j) * 32 + et * 16 + l15]);
      g = MFMA16(ag[ks], p.v, g);
    }
    float bgv = bg[et * 16 + l15];
#pragma unroll
    for (int r = 0; r < 4; r++)
      Gs[et * 16 + l15][rg * 16 + quad * 4 + r] = g[r] + bgv;
  }

  // ---- preload this wave's A fragments (32 rows; X never re-read after)
  bf16x8 a[2][4];
#pragma unroll
  for (int mb = 0; mb < 2; mb++)
#pragma unroll
    for (int ks = 0; ks < 4; ks++)
      a[mb][ks] = *(const bf16x8*)&Xs[(wr * 32 + mb * 16 + l15) * 136 + ks * 32 + quad * 8];
  __syncthreads();  // barrier 2: Gs ready (last barrier)

  float oacc[8];
#pragma unroll
  for (int i = 0; i < 8; i++) oacc[i] = 0.f;

  // ---- gate double-buffer: preload e=0 as float4 rows
  float4 gbuf[2][2];
#pragma unroll
  for (int mb = 0; mb < 2; mb++)
    gbuf[0][mb] = *(const float4*)&Gs[0][wr * 32 + mb * 16 + quad * 4];

  const float* wbase = We + (size_t)(quad * 8) * 64 + u;

  // ---- expert loop: no barriers (&3 ring + unroll 4, SROA-safe)
#pragma unroll 4
  for (int e = 0; e < E_DIM; ++e) {
    const int c = e & 3;
    const int gp = e & 1;

    // prefetch fp32 B for e+3 into the slot last used by e-1 (consumed)
    if (e + 3 < E_DIM) {
#pragma unroll
      for (int ks = 0; ks < 4; ks++)
#pragma unroll
        for (int j = 0; j < 8; j++)
          bw[(e + 3) & 3][ks][j] = wbase[(size_t)(e + 3) * 8192 + (ks * 32 + j) * 64];
      bevb[(e + 3) & 3] = be[(e + 3) * U_DIM + u];
    }
    // prefetch gate rows for e+1 (hidden under e's MFMAs)
    if (e + 1 < E_DIM) {
#pragma unroll
      for (int mb = 0; mb < 2; mb++)
        gbuf[gp ^ 1][mb] = *(const float4*)&Gs[e + 1][wr * 32 + mb * 16 + quad * 4];
    }

    // convert this expert's fp32 slot -> bf16 fragments (consume-time: the
    // s_waitcnt for slot c's loads lands HERE, 3 iterations after issue)
    bf16x8 bb[4];
#pragma unroll
    for (int ks = 0; ks < 4; ks++) {
      union { unsigned short us[8]; bf16x8 v; } p;
#pragma unroll
      for (int j = 0; j < 8; j++) p.us[j] = f2bf(bw[c][ks][j]);
      bb[ks] = p.v;
    }

    const float bev = bevb[c];
    floatx4 h[2];
#pragma unroll
    for (int mb = 0; mb < 2; mb++) h[mb] = {bev, bev, bev, bev};
#pragma unroll
    for (int ks = 0; ks < 4; ks++)
#pragma unroll
      for (int mb = 0; mb < 2; mb++)
        h[mb] = MFMA16(a[mb][ks], bb[ks], h[mb]);

    // epilogue: out += gate * leaky(h),  leaky(t) = max(t, 0.01t)
#pragma unroll
    for (int mb = 0; mb < 2; mb++) {
      const float4 g4 = gbuf[gp][mb];
      const float gr[4] = {g4.x, g4.y, g4.z, g4.w};
#pragma unroll
      for (int r = 0; r < 4; r++) {
        float t = h[mb][r];
        t = fmaxf(t, 0.01f * t);
        oacc[mb * 4 + r] = fmaf(gr[r], t, oacc[mb * 4 + r]);
      }
    }
  }

  // ---- store
#pragma unroll
  for (int mb = 0; mb < 2; mb++)
#pragma unroll
    for (int r = 0; r < 4; r++)
      out[(size_t)(base + wr * 32 + mb * 16 + quad * 4 + r) * U_DIM + u] = oacc[mb * 4 + r];
}

extern "C" void kernel_launch(void* const* d_in, const int* in_sizes, int n_in,
                              void* d_out, int out_size, void* d_ws, size_t ws_size,
                              hipStream_t stream) {
  const float* x  = (const float*)d_in[0];
  const float* Wg = (const float*)d_in[1];
  const float* bg = (const float*)d_in[2];
  const float* We = (const float*)d_in[3];
  const float* be = (const float*)d_in[4];
  (void)in_sizes; (void)n_in; (void)out_size; (void)d_ws; (void)ws_size;

  moe_main<<<N_TOK / 64, 512, 0, stream>>>(x, Wg, bg, We, be, (float*)d_out);
}

// Round 14
// 87.473 us; speedup vs baseline: 1.1151x; 1.1151x over previous
//
#include <hip/hip_runtime.h>
#include <stdint.h>

#define N_TOK 16384
#define F_DIM 128
#define U_DIM 64
#define E_DIM 32

typedef __bf16 bf16x8 __attribute__((ext_vector_type(8)));
typedef float  floatx4 __attribute__((ext_vector_type(4)));

#define MFMA16(a, b, c) __builtin_amdgcn_mfma_f32_16x16x32_bf16((a), (b), (c), 0, 0, 0)

__device__ __forceinline__ unsigned short f2bf(float f) {
  union { float f; unsigned u; } v; v.f = f;
  unsigned r = v.u + 0x7FFFu + ((v.u >> 16) & 1u);  // RNE
  return (unsigned short)(r >> 16);
}

// 8 fp32 -> 16B of bf16 via native casts (compiler emits v_cvt_pk_bf16_f32,
// RNE — bit-identical to f2bf on finite values, ~4x fewer VALU ops)
__device__ __forceinline__ uint4 cvt8pack(const float* w) {
  union { __bf16 b[8]; uint4 q; } p;
#pragma unroll
  for (int j = 0; j < 8; j++) p.b[j] = (__bf16)w[j];
  return p.q;
}

// ---------------------------------------------------------------------------
// Fused single kernel, LDS-pipelined B.
//
// R13 diagnosis: VGPR=128 allocation -> compiler SINKS prefetch loads to
// their consume points -> every expert serializes on one L2 round-trip
// (60% idle, MfmaUtil 7.6%). All prior register-ring variants (R0-R12)
// shared this sunk-load skeleton, which is why waves/warming/line-state/
// byte-volume levers were all null. Fix: pipeline B through LDS with
// mechanically-pinned placement:
//   per expert e: { issue 16 coalesced fp32 loads of B(e+2) -> w regs;
//                   convert w=B(e+1) (native casts) -> ds_write buf^1;
//                   s_waitcnt lgkmcnt(0); sched_barrier(0);   <- pin fence
//                   8 MFMA + epilogue;
//                   s_barrier (RAW - never drains vmcnt; __syncthreads'
//                   vmcnt(0) drain was R2's 136us bug) }
// sched_barrier(0) stops the scheduler moving loads/ds ops below the fence,
// so load-issue sits a full iteration (~400cyc) ahead of consume. In-flight
// state = 16 VGPRs -> no pressure to sink. Cold-immune: reads stable inputs
// (R13: cold 45.2 vs warm 42.5), no prep, no ws.
//
// B LDS layout: prep's verified fragment-linear layout with group stride
// 528 (pad +16): elem (ks*4+quad)*528 + u*8 + j == We[e][ks*32+quad*8+j][u].
// Write: wave writes 1024B contiguous (conflict-free). Read b128: pad makes
// quads land on distinct bank phases -> 2-way aliasing (free, m136).
// ---------------------------------------------------------------------------
__global__ __launch_bounds__(512, 1) void moe_fused(
    const float* __restrict__ x,
    const float* __restrict__ Wg,
    const float* __restrict__ bg,
    const float* __restrict__ We,
    const float* __restrict__ be,
    float* __restrict__ out) {
  __shared__ __align__(16) unsigned short Xs[64 * 136];   // 17.4 KB
  __shared__ __align__(16) float Gs[E_DIM][68];           // 8.7 KB
  __shared__ __align__(16) unsigned short Bs[2][16 * 528];// 33.8 KB (59.9 total)

  const int tid  = threadIdx.x;
  const int lane = tid & 63;
  const int wid  = tid >> 6;       // 0..7
  const int quad = lane >> 4;
  const int l15  = lane & 15;
  const int wr   = wid >> 2;       // 0..1 row half
  const int wc   = wid & 3;        // 0..3 u quarter
  const int u    = wc * 16 + l15;
  const int base = blockIdx.x * 64;

  // Staging geometry (mirrors prep exactly): group m = wid (round 0) and
  // wid+8 (round 1); ks=m>>2, qd=m&3, f0=ks*32+qd*8; lane = u (coalesced:
  // wave reads 64 consecutive floats = 256B per instruction).
  const int f0 = (wid >> 2) * 32 + (wid & 3) * 8;
  const float* ws0 = We + f0 * 64 + lane;   // round 1 = ws0 + 4096 (f0+64)

  // ---- prologue: issue B(0) loads
  float w0[8], w1[8];
#pragma unroll
  for (int j = 0; j < 8; j++) { w0[j] = ws0[j * 64]; w1[j] = ws0[4096 + j * 64]; }
  float bevCur = be[u];
  float bevNxt = be[U_DIM + u];

  // ---- stage X tile (fp32 -> bf16) into LDS (verified R1/R13 code)
  {
    const int row = tid >> 3;
    const int c16 = tid & 7;
    const float4* src = (const float4*)(x + (size_t)(base + row) * F_DIM + c16 * 16);
    float4 v0 = src[0], v1 = src[1], v2 = src[2], v3 = src[3];
    union { unsigned short us[16]; uint4 q[2]; } pk;
    pk.us[0]  = f2bf(v0.x); pk.us[1]  = f2bf(v0.y); pk.us[2]  = f2bf(v0.z); pk.us[3]  = f2bf(v0.w);
    pk.us[4]  = f2bf(v1.x); pk.us[5]  = f2bf(v1.y); pk.us[6]  = f2bf(v1.z); pk.us[7]  = f2bf(v1.w);
    pk.us[8]  = f2bf(v2.x); pk.us[9]  = f2bf(v2.y); pk.us[10] = f2bf(v2.z); pk.us[11] = f2bf(v2.w);
    pk.us[12] = f2bf(v3.x); pk.us[13] = f2bf(v3.y); pk.us[14] = f2bf(v3.z); pk.us[15] = f2bf(v3.w);
    uint4* dst = (uint4*)&Xs[row * 136 + c16 * 16];
    dst[0] = pk.q[0];
    dst[1] = pk.q[1];
  }

  // ---- publish B(0) into Bs[0]; issue B(1) loads
  *(uint4*)&Bs[0][wid * 528 + lane * 8]       = cvt8pack(w0);
  *(uint4*)&Bs[0][(wid + 8) * 528 + lane * 8] = cvt8pack(w1);
#pragma unroll
  for (int j = 0; j < 8; j++) { w0[j] = ws0[8192 + j * 64]; w1[j] = ws0[8192 + 4096 + j * 64]; }
  __syncthreads();  // barrier 1: Xs + Bs[0] ready (one-time full drain, ok)

  // ---- gate: wave (rg, et); Wg fp32 direct (verified R13 code)
  {
    const int rg = wid >> 1;
    const int et = wid & 1;
    bf16x8 ag[4];
#pragma unroll
    for (int ks = 0; ks < 4; ks++)
      ag[ks] = *(const bf16x8*)&Xs[(rg * 16 + l15) * 136 + ks * 32 + quad * 8];
    floatx4 g = {0.f, 0.f, 0.f, 0.f};
#pragma unroll
    for (int ks = 0; ks < 4; ks++) {
      union { unsigned short us[8]; bf16x8 v; } p;
#pragma unroll
      for (int j = 0; j < 8; j++)
        p.us[j] = f2bf(Wg[(size_t)(ks * 32 + quad * 8 + j) * 32 + et * 16 + l15]);
      g = MFMA16(ag[ks], p.v, g);
    }
    float bgv = bg[et * 16 + l15];
#pragma unroll
    for (int r = 0; r < 4; r++)
      Gs[et * 16 + l15][rg * 16 + quad * 4 + r] = g[r] + bgv;
  }

  // ---- preload this wave's A fragments (Xs never re-read after)
  bf16x8 a[2][4];
#pragma unroll
  for (int mb = 0; mb < 2; mb++)
#pragma unroll
    for (int ks = 0; ks < 4; ks++)
      a[mb][ks] = *(const bf16x8*)&Xs[(wr * 32 + mb * 16 + l15) * 136 + ks * 32 + quad * 8];
  __syncthreads();  // barrier 2: Gs ready

  float oacc[8];
#pragma unroll
  for (int i = 0; i < 8; i++) oacc[i] = 0.f;

  const unsigned short* rB = Bs[0];
  unsigned short*       wB = Bs[1];

  // ---- expert loop: one RAW barrier per expert, vmcnt never drained
  for (int e = 0; e < E_DIM; ++e) {
    // fragment + gate reads from LDS (B(e) complete: written pre-barrier)
    bf16x8 bb[4];
#pragma unroll
    for (int ks = 0; ks < 4; ks++)
      bb[ks] = *(const bf16x8*)&rB[(ks * 4 + quad) * 528 + u * 8];
    float4 gc0 = *(const float4*)&Gs[e][wr * 32 + quad * 4];
    float4 gc1 = *(const float4*)&Gs[e][wr * 32 + 16 + quad * 4];

    // convert B(e+1) (regs issued last iter, ~1 iter in flight) -> wB,
    // then issue B(e+2) loads into the freed regs
    if (e < E_DIM - 1) {
      *(uint4*)&wB[wid * 528 + lane * 8]       = cvt8pack(w0);
      *(uint4*)&wB[(wid + 8) * 528 + lane * 8] = cvt8pack(w1);
      if (e < E_DIM - 2) {
        const float* s = ws0 + (size_t)(e + 2) * 8192;
#pragma unroll
        for (int j = 0; j < 8; j++) { w0[j] = s[j * 64]; w1[j] = s[4096 + j * 64]; }
      }
    }
    float bevNew = (e < E_DIM - 2) ? be[(e + 2) * U_DIM + u] : 0.f;

    // fence: ds ops complete; nothing crosses (pins load issue ABOVE the
    // MFMA block -> a full iteration of work before their consume)
    asm volatile("s_waitcnt lgkmcnt(0)" ::: "memory");
    __builtin_amdgcn_sched_barrier(0);

    floatx4 h0 = {bevCur, bevCur, bevCur, bevCur};
    floatx4 h1 = h0;
#pragma unroll
    for (int ks = 0; ks < 4; ks++) {
      h0 = MFMA16(a[0][ks], bb[ks], h0);
      h1 = MFMA16(a[1][ks], bb[ks], h1);
    }

    // epilogue: out += gate * leaky(h)
    {
      const float g0[4] = {gc0.x, gc0.y, gc0.z, gc0.w};
      const float g1[4] = {gc1.x, gc1.y, gc1.z, gc1.w};
#pragma unroll
      for (int r = 0; r < 4; r++) {
        float t0 = h0[r]; t0 = fmaxf(t0, 0.01f * t0);
        oacc[r]     = fmaf(g0[r], t0, oacc[r]);
        float t1 = h1[r]; t1 = fmaxf(t1, 0.01f * t1);
        oacc[4 + r] = fmaf(g1[r], t1, oacc[4 + r]);
      }
    }
    bevCur = bevNxt;
    bevNxt = bevNew;

    if (e < E_DIM - 1) {
      __builtin_amdgcn_s_barrier();  // raw: B(e+1) visible; in-flight loads live on
      const unsigned short* t = rB; rB = wB; wB = (unsigned short*)t;
    }
  }

  // ---- store (verified R1 code)
#pragma unroll
  for (int mb = 0; mb < 2; mb++)
#pragma unroll
    for (int r = 0; r < 4; r++)
      out[(size_t)(base + wr * 32 + mb * 16 + quad * 4 + r) * U_DIM + u] = oacc[mb * 4 + r];
}

extern "C" void kernel_launch(void* const* d_in, const int* in_sizes, int n_in,
                              void* d_out, int out_size, void* d_ws, size_t ws_size,
                              hipStream_t stream) {
  const float* x  = (const float*)d_in[0];
  const float* Wg = (const float*)d_in[1];
  const float* bg = (const float*)d_in[2];
  const float* We = (const float*)d_in[3];
  const float* be = (const float*)d_in[4];
  (void)in_sizes; (void)n_in; (void)out_size; (void)d_ws; (void)ws_size;

  moe_fused<<<N_TOK / 64, 512, 0, stream>>>(x, Wg, bg, We, be, (float*)d_out);
}

// Round 15
// 79.659 us; speedup vs baseline: 1.2245x; 1.0981x over previous
//
#include <hip/hip_runtime.h>
#include <stdint.h>

#define N_TOK 16384
#define F_DIM 128
#define U_DIM 64
#define E_DIM 32

typedef __bf16 bf16x8 __attribute__((ext_vector_type(8)));
typedef float  floatx4 __attribute__((ext_vector_type(4)));

#define MFMA16(a, b, c) __builtin_amdgcn_mfma_f32_16x16x32_bf16((a), (b), (c), 0, 0, 0)

__device__ __forceinline__ unsigned short f2bf(float f) {
  union { float f; unsigned u; } v; v.f = f;
  unsigned r = v.u + 0x7FFFu + ((v.u >> 16) & 1u);  // RNE
  return (unsigned short)(r >> 16);
}

// ---------------------------------------------------------------------------
// Prep: fragment-linear bf16 weights in ws (verified layout). Minimal-work
// pre-pass: 4 MB coalesced read, 520 KB write. Keeping the two-kernel split
// is measured-optimal: fused variants (R13/R14) do the fp32->bf16 work
// inside the expert loop and run 10+ us slower in the post-fill regime.
//  wsWe elem idx: ((e*4+ks)*4+quad)*512 + u*8 + j   == We[e][ks*32+quad*8+j][u]
//  wsWg elem idx: ((et*4+ks)*64 + lane)*8 + j       == Wg[ks*32+(lane>>4)*8+j][et*16+(lane&15)]
// ---------------------------------------------------------------------------
__global__ __launch_bounds__(256) void moe_prep(
    const float* __restrict__ Wg, const float* __restrict__ We,
    unsigned short* __restrict__ wsWe, unsigned short* __restrict__ wsWg) {
  int t = blockIdx.x * 256 + threadIdx.x;
  if (t < 32768) {
    int u = t & 63, quad = (t >> 6) & 3, ks = (t >> 8) & 3, e = t >> 10;
    int f0 = ks * 32 + quad * 8;
    const float* src = We + e * 8192 + f0 * 64 + u;
    union { unsigned short us[8]; uint4 q; } p;
#pragma unroll
    for (int j = 0; j < 8; j++) p.us[j] = f2bf(src[j * 64]);
    *(uint4*)(wsWe + t * 8) = p.q;
  } else if (t < 32768 + 512) {
    int t2 = t - 32768;
    int l15 = t2 & 15, quad = (t2 >> 4) & 3, ks = (t2 >> 6) & 3, et = t2 >> 8;
    int e = et * 16 + l15, f0 = ks * 32 + quad * 8;
    union { unsigned short us[8]; uint4 q; } p;
#pragma unroll
    for (int j = 0; j < 8; j++) p.us[j] = f2bf(Wg[(f0 + j) * 32 + e]);
    *(uint4*)(wsWg + t2 * 8) = p.q;
  }
}

// ---------------------------------------------------------------------------
// Main: the measured-best structure (79.7-79.8 us total; 13.8 us warm via
// R3's x3-launch probe). 256 wgs x 512 thr (8 waves, 2/SIMD). Depth-4 B
// register ring, &3 indexing + #pragma unroll 4 — the ONLY ring recipe SROA
// keeps in registers (deeper or non-pow2 rings demote to scratch: R5-R7,
// 234 MB spill traffic). Minimum in-loop work: 4 dwordx4 B-loads + 1 be
// load per expert-thread; gate rows double-buffered from LDS; 2 barriers
// total. Session ledger (14 rounds): occupancy, prefetch depth, staging
// mechanism (reg/LDS-DMA/LDS-pipeline), L2 warming, line state, byte
// volume, tile shape, and prep-fusion all null or negative — wall time is
// set by the post-poison-fill regime (fill 42 us at 80% HBM peak + main's
// regime-inflated ~32 us), not by in-kernel structure.
// ---------------------------------------------------------------------------
__global__ __launch_bounds__(512, 2) void moe_main(
    const float* __restrict__ x,
    const float* __restrict__ bg,
    const float* __restrict__ be,
    const unsigned short* __restrict__ wsWe,
    const unsigned short* __restrict__ wsWg,
    float* __restrict__ out) {
  __shared__ unsigned short Xs[64 * 136];  // padded rows
  __shared__ float Gs[E_DIM][68];          // gate [e][row], padded

  const int tid  = threadIdx.x;
  const int lane = tid & 63;
  const int wid  = tid >> 6;       // 0..7
  const int quad = lane >> 4;
  const int l15  = lane & 15;
  const int wr   = wid >> 2;       // 0..1 row half
  const int wc   = wid & 3;        // 0..3 u quarter
  const int u    = wc * 16 + l15;
  const int base = blockIdx.x * 64;

  // ---- B ring: prefetch experts 0..2 before anything else
  bf16x8 bbuf[4][4];
  float bevb[4];
#pragma unroll
  for (int e0 = 0; e0 < 3; e0++) {
#pragma unroll
    for (int ks = 0; ks < 4; ks++)
      bbuf[e0][ks] = *(const bf16x8*)(wsWe + (size_t)((e0 * 4 + ks) * 4 + quad) * 512 + u * 8);
    bevb[e0] = be[e0 * U_DIM + u];
  }

  // ---- stage X tile (fp32 -> bf16) into LDS: 512 thr x 16 floats = 64x128
  {
    const int row = tid >> 3;
    const int c16 = tid & 7;
    const float4* src = (const float4*)(x + (size_t)(base + row) * F_DIM + c16 * 16);
    float4 v0 = src[0], v1 = src[1], v2 = src[2], v3 = src[3];
    union { unsigned short us[16]; uint4 q[2]; } pk;
    pk.us[0]  = f2bf(v0.x); pk.us[1]  = f2bf(v0.y); pk.us[2]  = f2bf(v0.z); pk.us[3]  = f2bf(v0.w);
    pk.us[4]  = f2bf(v1.x); pk.us[5]  = f2bf(v1.y); pk.us[6]  = f2bf(v1.z); pk.us[7]  = f2bf(v1.w);
    pk.us[8]  = f2bf(v2.x); pk.us[9]  = f2bf(v2.y); pk.us[10] = f2bf(v2.z); pk.us[11] = f2bf(v2.w);
    pk.us[12] = f2bf(v3.x); pk.us[13] = f2bf(v3.y); pk.us[14] = f2bf(v3.z); pk.us[15] = f2bf(v3.w);
    uint4* dst = (uint4*)&Xs[row * 136 + c16 * 16];
    dst[0] = pk.q[0];
    dst[1] = pk.q[1];
  }
  __syncthreads();  // barrier 1: X ready

  // ---- gate: 8 waves, wave = (rowgroup rg, expert-half et)
  {
    const int rg = wid >> 1;   // 0..3 -> rows rg*16..
    const int et = wid & 1;    // 0..1 -> experts et*16..
    bf16x8 ag[4];
#pragma unroll
    for (int ks = 0; ks < 4; ks++)
      ag[ks] = *(const bf16x8*)&Xs[(rg * 16 + l15) * 136 + ks * 32 + quad * 8];
    floatx4 g = {0.f, 0.f, 0.f, 0.f};
#pragma unroll
    for (int ks = 0; ks < 4; ks++) {
      bf16x8 wb = *(const bf16x8*)(wsWg + (size_t)((et * 4 + ks) * 64 + lane) * 8);
      g = MFMA16(ag[ks], wb, g);
    }
    float bgv = bg[et * 16 + l15];
#pragma unroll
    for (int r = 0; r < 4; r++)
      Gs[et * 16 + l15][rg * 16 + quad * 4 + r] = g[r] + bgv;
  }

  // ---- preload this wave's A fragments (32 rows; X never re-read after)
  bf16x8 a[2][4];
#pragma unroll
  for (int mb = 0; mb < 2; mb++)
#pragma unroll
    for (int ks = 0; ks < 4; ks++)
      a[mb][ks] = *(const bf16x8*)&Xs[(wr * 32 + mb * 16 + l15) * 136 + ks * 32 + quad * 8];
  __syncthreads();  // barrier 2: Gs ready (last barrier)

  float oacc[8];
#pragma unroll
  for (int i = 0; i < 8; i++) oacc[i] = 0.f;

  // ---- gate double-buffer: preload e=0 as float4 rows
  float4 gbuf[2][2];
#pragma unroll
  for (int mb = 0; mb < 2; mb++)
    gbuf[0][mb] = *(const float4*)&Gs[0][wr * 32 + mb * 16 + quad * 4];

  // ---- expert loop: no barriers (&3 ring + unroll 4, SROA-safe)
#pragma unroll 4
  for (int e = 0; e < E_DIM; ++e) {
    const int c = e & 3;
    const int gp = e & 1;

    // prefetch B for e+3 into the slot last used by e-1 (consumed)
    if (e + 3 < E_DIM) {
#pragma unroll
      for (int ks = 0; ks < 4; ks++)
        bbuf[(e + 3) & 3][ks] =
            *(const bf16x8*)(wsWe + (size_t)(((e + 3) * 4 + ks) * 4 + quad) * 512 + u * 8);
      bevb[(e + 3) & 3] = be[(e + 3) * U_DIM + u];
    }
    // prefetch gate rows for e+1 (hidden under e's MFMAs)
    if (e + 1 < E_DIM) {
#pragma unroll
      for (int mb = 0; mb < 2; mb++)
        gbuf[gp ^ 1][mb] = *(const float4*)&Gs[e + 1][wr * 32 + mb * 16 + quad * 4];
    }

    const float bev = bevb[c];
    floatx4 h[2];
#pragma unroll
    for (int mb = 0; mb < 2; mb++) h[mb] = {bev, bev, bev, bev};
#pragma unroll
    for (int ks = 0; ks < 4; ks++)
#pragma unroll
      for (int mb = 0; mb < 2; mb++)
        h[mb] = MFMA16(a[mb][ks], bbuf[c][ks], h[mb]);

    // epilogue: out += gate * leaky(h),  leaky(t) = max(t, 0.01t)
#pragma unroll
    for (int mb = 0; mb < 2; mb++) {
      const float4 g4 = gbuf[gp][mb];
      const float gr[4] = {g4.x, g4.y, g4.z, g4.w};
#pragma unroll
      for (int r = 0; r < 4; r++) {
        float t = h[mb][r];
        t = fmaxf(t, 0.01f * t);
        oacc[mb * 4 + r] = fmaf(gr[r], t, oacc[mb * 4 + r]);
      }
    }
  }

  // ---- store
#pragma unroll
  for (int mb = 0; mb < 2; mb++)
#pragma unroll
    for (int r = 0; r < 4; r++)
      out[(size_t)(base + wr * 32 + mb * 16 + quad * 4 + r) * U_DIM + u] = oacc[mb * 4 + r];
}

extern "C" void kernel_launch(void* const* d_in, const int* in_sizes, int n_in,
                              void* d_out, int out_size, void* d_ws, size_t ws_size,
                              hipStream_t stream) {
  const float* x  = (const float*)d_in[0];
  const float* Wg = (const float*)d_in[1];
  const float* bg = (const float*)d_in[2];
  const float* We = (const float*)d_in[3];
  const float* be = (const float*)d_in[4];
  unsigned short* wsWe = (unsigned short*)d_ws;              // 512 KB
  unsigned short* wsWg = wsWe + E_DIM * U_DIM * F_DIM;       // +8 KB
  (void)in_sizes; (void)n_in; (void)out_size; (void)ws_size;

  moe_prep<<<130, 256, 0, stream>>>(Wg, We, wsWe, wsWg);
  moe_main<<<N_TOK / 64, 512, 0, stream>>>(x, bg, be, wsWe, wsWg, (float*)d_out);
}